// Round 2
// baseline (542.062 us; speedup 1.0000x reference)
//
#include <hip/hip_runtime.h>

#define DEVFN __device__ __forceinline__

typedef float  f32x4  __attribute__((ext_vector_type(4)));
typedef short  bf16x8 __attribute__((ext_vector_type(8)));

// Problem constants
constexpr int ENC = 168;
constexpr int DEC = 24;
constexpr int BT  = 16;            // batch tile (MFMA N) per half
constexpr int NBLK = 4096 / (2 * BT);  // 128 blocks, 2 halves each

constexpr float LOG2E  = 1.4426950408889634f;
constexpr float LOG2E2 = 2.8853900817779268f;

// Workspace layout. ushort region: bf16 weight fragments [c][tt16][lane64][j8]
// K-maps: L0: k<20 x (c0), k==20 dup of col0 (lo-plane), k in[32,96) h0 (c1,c2)
//         L1: k<64 h0 (c1,c2), k in[64,128) h1 (c3,c4)
//         DEC: k<20 xin (c0), k==20 dup col0, k in[32,96) h1 (c3,c4)
constexpr int W0F = 0;             // 3*16*512 = 24576 ushorts
constexpr int W1F = 24576;         // 4*16*512 = 32768
constexpr int WDF = 57344;         // 3*16*512 = 24576
// float region (float indices; ushort total 81920 = 163840 B = 40960 floats)
constexpr int F_B0   = 40960;
constexpr int F_B1   = 41216;
constexpr int F_BD   = 41472;
constexpr int F_WOUT = 41728;
constexpr int F_BOUT = 41792;
constexpr int F_EMB  = 41793;      // [574] hour120 wd24 mo52 woy378
constexpr int NEMB = 574;

DEVFN ushort f2bf(float v) {       // fp32 -> bf16 bits, RNE (scalar path)
    unsigned b = __float_as_uint(v);
    return (ushort)((b + 0x7FFFu + ((b >> 16) & 1u)) >> 16);
}
DEVFN float bf2f(ushort u) { return __uint_as_float(((unsigned)u) << 16); }
DEVFN unsigned cvt_pk_bf16(float a, float b) {  // hw packed RNE
    unsigned r;
    asm("v_cvt_pk_bf16_f32 %0, %1, %2" : "=v"(r) : "v"(a), "v"(b));
    return r;
}
DEVFN float exp2n(float x) {       // 2^(-x), neg as free input modifier
    float r;
    asm("v_exp_f32 %0, -%1" : "=v"(r) : "v"(x));
    return r;
}
// pin a value into registers: asm consumes+redefines it -> no remat of the load
DEVFN void pinv(bf16x8& v) { asm volatile("" : "+v"(v)); }
DEVFN void pinf(f32x4& v)  { asm volatile("" : "+v"(v)); }

// LSTM cell on pre-scaled gates (i,f,o x log2e; g x 2log2e), fused-rcp pairs.
DEVFN float lstm_cell(float gi, float gf, float gg, float go, float& c) {
    float a  = exp2n(fmaxf(gi, -21.f));            // e^-i
    float b  = exp2n(fmaxf(gg, -43.f));            // e^-2g
    float f  = exp2n(gf);                          // e^-f
    float sf = __builtin_amdgcn_rcpf(1.f + f);
    float it = (1.f - b) * __builtin_amdgcn_rcpf(fmaf(a, b, a + b + 1.f));
    c = fmaf(sf, c, it);
    float d  = exp2n(fmaxf(c, -15.f) * LOG2E2);    // e^-2c
    float o  = exp2n(fmaxf(go, -21.f));            // e^-o
    return (1.f - d) * __builtin_amdgcn_rcpf(fmaf(o, d, o + d + 1.f));
}

// ---------------- prep: weights -> bf16 MFMA fragments (pre-scaled) --------
// EXACT layout of the verified round-0 kernel (gate-major tiles g*4+wl).
__global__ void prep_kernel(
    const float* __restrict__ w0ih, const float* __restrict__ w0hh,
    const float* __restrict__ b0ih, const float* __restrict__ b0hh,
    const float* __restrict__ w1ih, const float* __restrict__ w1hh,
    const float* __restrict__ b1ih, const float* __restrict__ b1hh,
    const float* __restrict__ wdih, const float* __restrict__ wdhh,
    const float* __restrict__ bdih, const float* __restrict__ bdhh,
    const float* __restrict__ wout, const float* __restrict__ boutp,
    const float* __restrict__ eh,   const float* __restrict__ ewd,
    const float* __restrict__ emo,  const float* __restrict__ ewoy,
    void* __restrict__ ws)
{
    ushort* wsu = (ushort*)ws;
    float*  wsf = (float*)ws;
    const int total = 81920 + 1407;
    for (int idx = blockIdx.x * blockDim.x + threadIdx.x; idx < total;
         idx += gridDim.x * blockDim.x) {
        if (idx < 81920) {
            int layer, q;
            if (idx < W1F)      { layer = 0; q = idx; }
            else if (idx < WDF) { layer = 1; q = idx - W1F; }
            else                { layer = 2; q = idx - WDF; }
            int c  = q >> 13;
            int tt = (q >> 9) & 15;
            int l  = (q >> 3) & 63;
            int j  = q & 7;
            int k  = c * 32 + (l >> 4) * 8 + j;
            int n  = tt * 16 + (l & 15);
            float v = 0.f;
            if (layer == 0) {
                if (k < 20) v = w0ih[n * 20 + k];
                else if (k == 20) v = w0ih[n * 20];            // lo-plane dup of col0
                else if (k >= 32 && k < 96) v = w0hh[n * 64 + (k - 32)];
            } else if (layer == 1) {
                if (k < 64) v = w1ih[n * 64 + k];
                else        v = w1hh[n * 64 + (k - 64)];
            } else {
                if (k < 20) v = wdih[n * 20 + k];
                else if (k == 20) v = wdih[n * 20];            // lo-plane dup of col0
                else if (k >= 32 && k < 96) v = wdhh[n * 64 + (k - 32)];
            }
            v *= ((n >> 6) == 2) ? LOG2E2 : LOG2E;   // pre-scale for exp2
            wsu[idx] = f2bf(v);
        } else {
            int f = idx - 81920;
            float v;
            if (f < 768) {
                float sc = (((f & 255) >> 6) == 2) ? LOG2E2 : LOG2E;
                if (f < 256)      v = (b0ih[f] + b0hh[f]) * sc;
                else if (f < 512) v = (b1ih[f - 256] + b1hh[f - 256]) * sc;
                else              v = (bdih[f - 512] + bdhh[f - 512]) * sc;
            }
            else if (f < 832) v = wout[f - 768];
            else if (f == 832) v = boutp[0];
            else {
                int e = f - 833;
                if (e < 120)      v = eh[e];
                else if (e < 144) v = ewd[e - 120];
                else if (e < 196) v = emo[e - 144];
                else              v = ewoy[e - 196];
            }
            wsf[40960 + f] = v;
        }
    }
}

DEVFN int offX(int k, int m) {     // chunk0 fragment offset, k in [0,32)
    return (m + 16 * (k >> 3)) * 8 + (k & 7);
}
// packed: 4 consecutive-k h values -> one b64 write
DEVFN void store_h4(ushort* A, int off, const float* h) {
    unsigned h01 = cvt_pk_bf16(h[0], h[1]);
    unsigned h23 = cvt_pk_bf16(h[2], h[3]);
    asm volatile("" : "+v"(h01), "+v"(h23));
    unsigned long long p = ((unsigned long long)h23 << 32) | h01;
    *(unsigned long long*)(A + off) = p;
}
// hi/lo pair for the k=0 feature (label/prev): hi at k=0, lo at k=20
DEVFN void store_prev(ushort* A, int m, float v) {
    ushort hi = f2bf(v);
    A[offX(0, m)]  = hi;
    A[offX(20, m)] = f2bf(v - bf2f(hi));
}

// ---------------- main persistent MFMA kernel: 1024 thr = 2x old 512 -------
// Each 512-thread half is an exact copy of the verified round-0 kernel,
// operating on its own batch tile (b0g = blk*32 + half*16) with its own
// Abuf/sh1. Barriers are block-wide (superset of per-half sync). This
// doubles waves/SIMD (2 -> 4) for latency hiding with BIT-IDENTICAL math.
__global__ __launch_bounds__(1024)
__attribute__((amdgpu_waves_per_eu(4, 4)))
void lstm_mfma(
    const int* __restrict__ input_time, const float* __restrict__ label_p,
    const int* __restrict__ decoder_time, const void* __restrict__ ws,
    float* __restrict__ out)
{
    const ushort* wsu = (const ushort*)ws;
    const float*  wsf = (const float*)ws;

    // per-half double-buffered activations: c0=x/xin, c1c2=h0, c3c4=h1
    __shared__ __align__(16) ushort Abuf[2][2][5 * 512];
    __shared__ float s_emb[NEMB];
    __shared__ float s_wout[64];
    __shared__ float sh1[2][16 * 68];  // [half][m][u] padded
    __shared__ float s_bout;

    const int tid  = threadIdx.x;
    const int half = tid >> 9;         // 0 or 1
    const int stid = tid & 511;        // thread id within the half (old tid)
    const int w   = stid >> 6;         // wave-in-half 0..7
    const int l   = stid & 63;
    const int q   = l >> 4;
    const int m   = l & 15;
    const int wl  = w & 3;
    const bool isL0 = (w < 4);
    const int b0g = blockIdx.x * (2 * BT) + half * BT;
    const int u0  = wl * 16 + q * 4;   // this lane's 4 units

    ushort (* const AB)[5 * 512] = Abuf[half];
    float*  const  myh1 = sh1[half];

    // h fragment store offset: L0 -> c1c2 (base), L1/dec -> c3c4 (+1024)
    const int hoff = (1 + (u0 >> 5)) * 512 +
                     (m + 16 * ((u0 & 31) >> 3)) * 8 + (u0 & 7) +
                     (isL0 ? 0 : 1024);

    // ---- init (block-wide strides over all shared) ----
    for (int i = tid; i < 2 * 2 * 5 * 512; i += 1024) ((ushort*)Abuf)[i] = 0;
    for (int i = tid; i < NEMB; i += 1024) s_emb[i] = wsf[F_EMB + i];
    if (tid < 64) s_wout[tid] = wsf[F_WOUT + tid];
    if (tid == 0) s_bout = wsf[F_BOUT];

    // ---- weight fragments (A-operand, bf16), pinned register-resident ----
    bf16x8 wA[4][4];                   // [chunk][gamma]; L0/dec use [0..2][*]
    if (isL0) {
#pragma unroll
        for (int c = 0; c < 3; c++)
#pragma unroll
            for (int g = 0; g < 4; g++)
                wA[c][g] = *(const bf16x8*)(wsu + W0F +
                    (c * 16 + g * 4 + wl) * 512 + l * 8);
        wA[3][0] = wA[3][1] = wA[3][2] = wA[3][3] = bf16x8{0,0,0,0,0,0,0,0};
    } else {
#pragma unroll
        for (int c = 0; c < 4; c++)
#pragma unroll
            for (int g = 0; g < 4; g++)
                wA[c][g] = *(const bf16x8*)(wsu + W1F +
                    (c * 16 + g * 4 + wl) * 512 + l * 8);
    }
#pragma unroll
    for (int c = 0; c < 4; c++)
#pragma unroll
        for (int g = 0; g < 4; g++) pinv(wA[c][g]);

    f32x4 biasv[4];
#pragma unroll
    for (int g = 0; g < 4; g++) {
        biasv[g] = *(const f32x4*)(wsf + (isL0 ? F_B0 : F_B1) + g * 64 + u0);
        pinf(biasv[g]);
    }

    float cst[4] = {0.f, 0.f, 0.f, 0.f};

    // x-build roles (L0 waves only, per half): primary kk1 = stid>>4 (0..15);
    // secondary kk2 = kk1+16 (16..19) for stid<64. batch = stid&15 = m.
    const int kk1 = stid >> 4;
    const int kk2 = kk1 + 16;
    const bool bx2 = (stid < 64);
    // hoisted emb addressing: lookup = s_emb[ebase + idx*estr]
    int sel1 = 0, estr1 = 0, ebase1 = 0;
    if (kk1 >= 1) {
        int f = kk1 - 1;
        if (f < 5)       { sel1 = 0; estr1 = 5; ebase1 = 0   + f; }
        else if (f < 8)  { sel1 = 1; estr1 = 3; ebase1 = 120 + (f - 5); }
        else if (f < 12) { sel1 = 2; estr1 = 4; ebase1 = 144 + (f - 8); }
        else             { sel1 = 3; estr1 = 7; ebase1 = 196 + (f - 12); }
    }
    const int ebase2 = 196 + (kk2 - 13);   // woy table, stride 7

    __syncthreads();
    if (isL0) {    // x(0) into AB[0]
        if (kk1 == 0) {
            store_prev(AB[0], m, label_p[(b0g + m) * ENC]);
        } else {
            int idx = input_time[((b0g + m) * ENC) * 4 + sel1];
            AB[0][offX(kk1, m)] = f2bf(s_emb[ebase1 + idx * estr1]);
        }
        if (bx2) {
            int idx2 = input_time[((b0g + m) * ENC) * 4 + 3];
            AB[0][offX(kk2, m)] = f2bf(s_emb[ebase2 + idx2 * 7]);
        }
    }
    __syncthreads();

    // ============ encoder pipeline: iter i = layer0(i) + layer1(i-1) ========
    for (int i = 0; i <= ENC; ++i) {
        const ushort* Ar = AB[i & 1];
        ushort* Aw = AB[(i + 1) & 1];
        const bool active = isL0 ? (i < ENC) : (i >= 1);

        // prefetch globals for next x (L0 waves)
        float pre_f = 0.f; int pre_i1 = 0, pre_i2 = 0;
        const bool encX  = (i + 1 < ENC) && isL0;
        const bool decX0 = (i == ENC) && isL0;
        if (encX) {
            if (kk1 == 0) pre_f  = label_p[(b0g + m) * ENC + (i + 1)];
            else          pre_i1 = input_time[((b0g + m) * ENC + (i + 1)) * 4 + sel1];
            if (bx2)      pre_i2 = input_time[((b0g + m) * ENC + (i + 1)) * 4 + 3];
        } else if (decX0) {
            if (kk1 == 0) pre_f  = label_p[(b0g + m) * ENC + (ENC - 1)];
            else          pre_i1 = decoder_time[((b0g + m) * DEC) * 4 + sel1];
            if (bx2)      pre_i2 = decoder_time[((b0g + m) * DEC) * 4 + 3];
        }

        if (active) {
            f32x4 acc[4];
            if (isL0) {
                bf16x8 ah[3];
#pragma unroll
                for (int c = 0; c < 3; c++)
                    ah[c] = *(const bf16x8*)(Ar + c * 512 + l * 8);
#pragma unroll
                for (int g = 0; g < 4; g++)
                    acc[g] = __builtin_amdgcn_mfma_f32_16x16x32_bf16(
                        wA[0][g], ah[0], biasv[g], 0, 0, 0);
#pragma unroll
                for (int c = 1; c < 3; c++)
#pragma unroll
                    for (int g = 0; g < 4; g++)
                        acc[g] = __builtin_amdgcn_mfma_f32_16x16x32_bf16(
                            wA[c][g], ah[c], acc[g], 0, 0, 0);
            } else {
                bf16x8 ah[4];
#pragma unroll
                for (int c = 0; c < 4; c++)
                    ah[c] = *(const bf16x8*)(Ar + (1 + c) * 512 + l * 8);
#pragma unroll
                for (int g = 0; g < 4; g++)
                    acc[g] = __builtin_amdgcn_mfma_f32_16x16x32_bf16(
                        wA[0][g], ah[0], biasv[g], 0, 0, 0);
#pragma unroll
                for (int c = 1; c < 4; c++)
#pragma unroll
                    for (int g = 0; g < 4; g++)
                        acc[g] = __builtin_amdgcn_mfma_f32_16x16x32_bf16(
                            wA[c][g], ah[c], acc[g], 0, 0, 0);
            }
            float hv[4];
#pragma unroll
            for (int r = 0; r < 4; r++)
                hv[r] = lstm_cell(acc[0][r], acc[1][r], acc[2][r], acc[3][r], cst[r]);
            store_h4(Aw, hoff, hv);    // single store: h0->c1c2 or h1->c3c4
        }
        if (encX || decX0) {
            if (kk1 == 0) store_prev(Aw, m, pre_f);
            else          Aw[offX(kk1, m)] = f2bf(s_emb[ebase1 + pre_i1 * estr1]);
            if (bx2)      Aw[offX(kk2, m)] = f2bf(s_emb[ebase2 + pre_i2 * 7]);
        }
        __syncthreads();
    }

    // ============ decoder: waves 4-7 (per half) compute; L0 waves build x ===
    if (!isL0) {
#pragma unroll
        for (int c = 0; c < 3; c++)
#pragma unroll
            for (int g = 0; g < 4; g++)
                wA[c][g] = *(const bf16x8*)(wsu + WDF +
                    (c * 16 + g * 4 + wl) * 512 + l * 8);
#pragma unroll
        for (int c = 0; c < 3; c++)
#pragma unroll
            for (int g = 0; g < 4; g++) pinv(wA[c][g]);
#pragma unroll
        for (int g = 0; g < 4; g++) {
            biasv[g] = *(const f32x4*)(wsf + F_BD + g * 64 + u0);
            pinf(biasv[g]);
        }
    }

    for (int t = 0; t < DEC; ++t) {
        const ushort* Ar = AB[(t + 1) & 1];
        ushort* Aw = AB[t & 1];

        int pre_i1 = 0, pre_i2 = 0;
        const bool dX = (t + 1 < DEC) && isL0;
        if (dX) {
            if (kk1 >= 1) pre_i1 = decoder_time[((b0g + m) * DEC + (t + 1)) * 4 + sel1];
            if (bx2)      pre_i2 = decoder_time[((b0g + m) * DEC + (t + 1)) * 4 + 3];
        }

        if (!isL0) {
            bf16x8 ah[3];
            ah[0] = *(const bf16x8*)(Ar + 0 * 512 + l * 8);   // xin (c0)
            ah[1] = *(const bf16x8*)(Ar + 3 * 512 + l * 8);   // h1 lo (c3)
            ah[2] = *(const bf16x8*)(Ar + 4 * 512 + l * 8);   // h1 hi (c4)
            f32x4 acc[4];
#pragma unroll
            for (int g = 0; g < 4; g++)
                acc[g] = __builtin_amdgcn_mfma_f32_16x16x32_bf16(
                    wA[0][g], ah[0], biasv[g], 0, 0, 0);
#pragma unroll
            for (int c = 1; c < 3; c++)
#pragma unroll
                for (int g = 0; g < 4; g++)
                    acc[g] = __builtin_amdgcn_mfma_f32_16x16x32_bf16(
                        wA[c][g], ah[c], acc[g], 0, 0, 0);
            float hv[4];
#pragma unroll
            for (int r = 0; r < 4; r++)
                hv[r] = lstm_cell(acc[0][r], acc[1][r], acc[2][r], acc[3][r], cst[r]);
            store_h4(Aw, hoff, hv);                 // h1 recurrent -> c3c4
            *(f32x4*)&myh1[m * 68 + u0] = *(f32x4*)hv;
        }
        if (dX && kk1 >= 1) Aw[offX(kk1, m)] = f2bf(s_emb[ebase1 + pre_i1 * estr1]);
        if (dX && bx2)      Aw[offX(kk2, m)] = f2bf(s_emb[ebase2 + pre_i2 * 7]);
        __syncthreads();

        if (stid < 16) {   // serial projection, old summation order (exact)
            float a = s_bout;
#pragma unroll 16
            for (int u = 0; u < 64; u++) a = fmaf(s_wout[u], myh1[stid * 68 + u], a);
            out[(b0g + stid) * DEC + t] = a;
            if (t + 1 < DEC) store_prev(Aw, stid, a);  // fp32-accurate prev (hi+lo)
        }
        __syncthreads();
    }
}

extern "C" void kernel_launch(void* const* d_in, const int* in_sizes, int n_in,
                              void* d_out, int out_size, void* d_ws, size_t ws_size,
                              hipStream_t stream)
{
    typedef const float* fp;
    const int* input_time   = (const int*)d_in[1];
    fp         label_p      = (fp)d_in[2];
    const int* decoder_time = (const int*)d_in[3];

    prep_kernel<<<128, 256, 0, stream>>>(
        (fp)d_in[4],  (fp)d_in[5],  (fp)d_in[6],  (fp)d_in[7],
        (fp)d_in[8],  (fp)d_in[9],  (fp)d_in[10], (fp)d_in[11],
        (fp)d_in[12], (fp)d_in[13], (fp)d_in[14], (fp)d_in[15],
        (fp)d_in[16], (fp)d_in[17],
        (fp)d_in[18], (fp)d_in[19], (fp)d_in[20], (fp)d_in[21],
        d_ws);

    lstm_mfma<<<NBLK, 1024, 0, stream>>>(
        input_time, label_p, decoder_time, d_ws, (float*)d_out);
}

// Round 5
// 408.501 us; speedup vs baseline: 1.3270x; 1.3270x over previous
//
#include <hip/hip_runtime.h>

#define DEVFN __device__ __forceinline__

typedef float  f32x4  __attribute__((ext_vector_type(4)));
typedef short  bf16x8 __attribute__((ext_vector_type(8)));

// Problem constants
constexpr int ENC = 168;
constexpr int DEC = 24;
constexpr int BT  = 16;            // batch tile (MFMA N) per half
constexpr int NBLK = 4096 / (2 * BT);  // 128 blocks, 2 halves each

constexpr float LOG2E  = 1.4426950408889634f;
constexpr float LOG2E2 = 2.8853900817779268f;

// Workspace layout. ushort region: bf16 weight fragments [c][tt16][lane64][j8]
// (VERIFIED round-0/round-2 gate-major tile layout: tile tt = g*4 + wl,
//  row = unit within gate block; n = tt*16 + (l&15).)
// K-maps: L0: k<20 x (c0), k==20 dup of col0 (lo-plane), k in[32,96) h0 (c1,c2)
//         L1: k<64 h0 (c1,c2), k in[64,128) h1 (c3,c4)
//         DEC: k<20 xin (c0), k==20 dup col0, k in[32,96) h1 (c3,c4)
constexpr int W0F = 0;             // 3*16*512 = 24576 ushorts
constexpr int W1F = 24576;         // 4*16*512 = 32768
constexpr int WDF = 57344;         // 3*16*512 = 24576
// float region (float indices; ushort total 81920 = 163840 B = 40960 floats)
constexpr int F_B0   = 40960;
constexpr int F_B1   = 41216;
constexpr int F_BD   = 41472;
constexpr int F_WOUT = 41728;
constexpr int F_BOUT = 41792;
constexpr int F_EMB  = 41793;      // [574] hour120 wd24 mo52 woy378
constexpr int NEMB = 574;

DEVFN ushort f2bf(float v) {       // fp32 -> bf16 bits, RNE (scalar path)
    unsigned b = __float_as_uint(v);
    return (ushort)((b + 0x7FFFu + ((b >> 16) & 1u)) >> 16);
}
DEVFN float bf2f(ushort u) { return __uint_as_float(((unsigned)u) << 16); }
DEVFN unsigned cvt_pk_bf16(float a, float b) {  // hw packed RNE
    unsigned r;
    asm("v_cvt_pk_bf16_f32 %0, %1, %2" : "=v"(r) : "v"(a), "v"(b));
    return r;
}
DEVFN float exp2n(float x) {       // 2^(-x), neg as free input modifier
    float r;
    asm("v_exp_f32 %0, -%1" : "=v"(r) : "v"(x));
    return r;
}
// pin a value into registers: asm consumes+redefines it -> no remat of the load
DEVFN void pinv(bf16x8& v) { asm volatile("" : "+v"(v)); }
DEVFN void pinf(f32x4& v)  { asm volatile("" : "+v"(v)); }

// LSTM cell on pre-scaled gates (i,f,o x log2e; g x 2log2e), fused-rcp pairs.
DEVFN float lstm_cell(float gi, float gf, float gg, float go, float& c) {
    float a  = exp2n(fmaxf(gi, -21.f));            // e^-i
    float b  = exp2n(fmaxf(gg, -43.f));            // e^-2g
    float f  = exp2n(gf);                          // e^-f
    float sf = __builtin_amdgcn_rcpf(1.f + f);
    float it = (1.f - b) * __builtin_amdgcn_rcpf(fmaf(a, b, a + b + 1.f));
    c = fmaf(sf, c, it);
    float d  = exp2n(fmaxf(c, -15.f) * LOG2E2);    // e^-2c
    float o  = exp2n(fmaxf(go, -21.f));            // e^-o
    return (1.f - d) * __builtin_amdgcn_rcpf(fmaf(o, d, o + d + 1.f));
}

// ---------------- prep: weights -> bf16 MFMA fragments (pre-scaled) --------
// EXACT layout of the verified round-0/round-2 kernel (gate-major tiles).
__global__ void prep_kernel(
    const float* __restrict__ w0ih, const float* __restrict__ w0hh,
    const float* __restrict__ b0ih, const float* __restrict__ b0hh,
    const float* __restrict__ w1ih, const float* __restrict__ w1hh,
    const float* __restrict__ b1ih, const float* __restrict__ b1hh,
    const float* __restrict__ wdih, const float* __restrict__ wdhh,
    const float* __restrict__ bdih, const float* __restrict__ bdhh,
    const float* __restrict__ wout, const float* __restrict__ boutp,
    const float* __restrict__ eh,   const float* __restrict__ ewd,
    const float* __restrict__ emo,  const float* __restrict__ ewoy,
    void* __restrict__ ws)
{
    ushort* wsu = (ushort*)ws;
    float*  wsf = (float*)ws;
    const int total = 81920 + 1407;
    for (int idx = blockIdx.x * blockDim.x + threadIdx.x; idx < total;
         idx += gridDim.x * blockDim.x) {
        if (idx < 81920) {
            int layer, q;
            if (idx < W1F)      { layer = 0; q = idx; }
            else if (idx < WDF) { layer = 1; q = idx - W1F; }
            else                { layer = 2; q = idx - WDF; }
            int c  = q >> 13;
            int tt = (q >> 9) & 15;
            int l  = (q >> 3) & 63;
            int j  = q & 7;
            int k  = c * 32 + (l >> 4) * 8 + j;
            int n  = tt * 16 + (l & 15);
            float v = 0.f;
            if (layer == 0) {
                if (k < 20) v = w0ih[n * 20 + k];
                else if (k == 20) v = w0ih[n * 20];            // lo-plane dup of col0
                else if (k >= 32 && k < 96) v = w0hh[n * 64 + (k - 32)];
            } else if (layer == 1) {
                if (k < 64) v = w1ih[n * 64 + k];
                else        v = w1hh[n * 64 + (k - 64)];
            } else {
                if (k < 20) v = wdih[n * 20 + k];
                else if (k == 20) v = wdih[n * 20];            // lo-plane dup of col0
                else if (k >= 32 && k < 96) v = wdhh[n * 64 + (k - 32)];
            }
            v *= ((n >> 6) == 2) ? LOG2E2 : LOG2E;   // pre-scale for exp2
            wsu[idx] = f2bf(v);
        } else {
            int f = idx - 81920;
            float v;
            if (f < 768) {
                float sc = (((f & 255) >> 6) == 2) ? LOG2E2 : LOG2E;
                if (f < 256)      v = (b0ih[f] + b0hh[f]) * sc;
                else if (f < 512) v = (b1ih[f - 256] + b1hh[f - 256]) * sc;
                else              v = (bdih[f - 512] + bdhh[f - 512]) * sc;
            }
            else if (f < 832) v = wout[f - 768];
            else if (f == 832) v = boutp[0];
            else {
                int e = f - 833;
                if (e < 120)      v = eh[e];
                else if (e < 144) v = ewd[e - 120];
                else if (e < 196) v = emo[e - 144];
                else              v = ewoy[e - 196];
            }
            wsf[40960 + f] = v;
        }
    }
}

DEVFN int offX(int k, int m) {     // chunk0 fragment offset, k in [0,32)
    return (m + 16 * (k >> 3)) * 8 + (k & 7);
}
// packed: 4 consecutive-k h values -> one b64 write
DEVFN void store_h4(ushort* A, int off, const float* h) {
    unsigned h01 = cvt_pk_bf16(h[0], h[1]);
    unsigned h23 = cvt_pk_bf16(h[2], h[3]);
    asm volatile("" : "+v"(h01), "+v"(h23));
    unsigned long long p = ((unsigned long long)h23 << 32) | h01;
    *(unsigned long long*)(A + off) = p;
}
// hi/lo pair for the k=0 feature (label/prev): hi at k=0, lo at k=20
DEVFN void store_prev(ushort* A, int m, float v) {
    ushort hi = f2bf(v);
    A[offX(0, m)]  = hi;
    A[offX(20, m)] = f2bf(v - bf2f(hi));
}

// ---------------- main persistent MFMA kernel: 1024 thr = 2x old 512 -------
// Each 512-thread half executes EXACTLY the verified round-2 math on its own
// batch tile (b0g = blk*32 + half*16) with its own Abuf/sh1. Register diet
// vs round 2: weight chunks >=2 are served from a 48 KB LDS copy per step
// (same bits -> bit-identical MFMA inputs), so wA shrinks 64->32 VGPR and
// 16 waves fit the 128-VGPR cap WITHOUT spilling (round 2's failure mode).
__global__ __launch_bounds__(1024)
void lstm_mfma(
    const int* __restrict__ input_time, const float* __restrict__ label_p,
    const int* __restrict__ decoder_time, const void* __restrict__ ws,
    float* __restrict__ out)
{
    const ushort* wsu = (const ushort*)ws;
    const float*  wsf = (const float*)ws;

    // per-half double-buffered activations: c0=x/xin, c1c2=h0, c3c4=h1
    __shared__ __align__(16) ushort Abuf[2][2][5 * 512];
    // staged weight tail chunks: [0,8192) = W0 c2 (later WD c2),
    // [8192,16384) = W1 c2, [16384,24576) = W1 c3. 48 KB.
    __shared__ __align__(16) ushort sW[24576];
    __shared__ float s_emb[NEMB];
    __shared__ float s_wout[64];
    __shared__ float sh1[2][16 * 68];  // [half][m][u] padded
    __shared__ float s_bout;

    const int tid  = threadIdx.x;
    const int half = tid >> 9;         // 0 or 1
    const int stid = tid & 511;        // thread id within the half (old tid)
    const int w   = stid >> 6;         // wave-in-half 0..7
    const int l   = stid & 63;
    const int q   = l >> 4;
    const int m   = l & 15;
    const int wl  = w & 3;
    const bool isL0 = (w < 4);
    const int b0g = blockIdx.x * (2 * BT) + half * BT;
    const int u0  = wl * 16 + q * 4;   // this lane's 4 units

    ushort (* const AB)[5 * 512] = Abuf[half];
    float*  const  myh1 = sh1[half];

    // h fragment store offset: L0 -> c1c2 (base), L1/dec -> c3c4 (+1024)
    const int hoff = (1 + (u0 >> 5)) * 512 +
                     (m + 16 * ((u0 & 31) >> 3)) * 8 + (u0 & 7) +
                     (isL0 ? 0 : 1024);
    // per-wave fragment byte base within a staged chunk region (tt = g*4+wl)
    const int fbase = wl * 512 + l * 8;   // + g*2048 per gate

    // ---- init (block-wide strides over all shared) ----
    for (int i = tid; i < 2 * 2 * 5 * 512; i += 1024) ((ushort*)Abuf)[i] = 0;
    for (int i = tid; i < NEMB; i += 1024) s_emb[i] = wsf[F_EMB + i];
    if (tid < 64) s_wout[tid] = wsf[F_WOUT + tid];
    if (tid == 0) s_bout = wsf[F_BOUT];
    {   // stage weight tail chunks into LDS (one-time, 48 KB)
        const uint* g0 = (const uint*)(wsu + W0F + 2 * 8192);
        const uint* g1 = (const uint*)(wsu + W1F + 2 * 8192);
        const uint* g2 = (const uint*)(wsu + W1F + 3 * 8192);
        uint* d = (uint*)sW;
        for (int i = tid; i < 4096; i += 1024) {
            d[i]        = g0[i];
            d[4096 + i] = g1[i];
            d[8192 + i] = g2[i];
        }
    }

    // ---- head weight fragments (chunks 0,1) pinned register-resident ----
    bf16x8 wA[2][4];                   // [chunk][gamma]
    {
        const int wbase = isL0 ? W0F : W1F;
#pragma unroll
        for (int c = 0; c < 2; c++)
#pragma unroll
            for (int g = 0; g < 4; g++)
                wA[c][g] = *(const bf16x8*)(wsu + wbase +
                    (c * 16 + g * 4 + wl) * 512 + l * 8);
    }
#pragma unroll
    for (int c = 0; c < 2; c++)
#pragma unroll
        for (int g = 0; g < 4; g++) pinv(wA[c][g]);

    f32x4 biasv[4];
#pragma unroll
    for (int g = 0; g < 4; g++) {
        biasv[g] = *(const f32x4*)(wsf + (isL0 ? F_B0 : F_B1) + g * 64 + u0);
        pinf(biasv[g]);
    }

    float cst[4] = {0.f, 0.f, 0.f, 0.f};

    // x-build roles (L0 waves only, per half): primary kk1 = stid>>4 (0..15);
    // secondary kk2 = kk1+16 (16..19) for stid<64. batch = stid&15 = m.
    const int kk1 = stid >> 4;
    const int kk2 = kk1 + 16;
    const bool bx2 = (stid < 64);
    // hoisted emb addressing: lookup = s_emb[ebase + idx*estr]
    int sel1 = 0, estr1 = 0, ebase1 = 0;
    if (kk1 >= 1) {
        int f = kk1 - 1;
        if (f < 5)       { sel1 = 0; estr1 = 5; ebase1 = 0   + f; }
        else if (f < 8)  { sel1 = 1; estr1 = 3; ebase1 = 120 + (f - 5); }
        else if (f < 12) { sel1 = 2; estr1 = 4; ebase1 = 144 + (f - 8); }
        else             { sel1 = 3; estr1 = 7; ebase1 = 196 + (f - 12); }
    }
    const int ebase2 = 196 + (kk2 - 13);   // woy table, stride 7

    __syncthreads();
    if (isL0) {    // x(0) into AB[0]
        if (kk1 == 0) {
            store_prev(AB[0], m, label_p[(b0g + m) * ENC]);
        } else {
            int idx = input_time[((b0g + m) * ENC) * 4 + sel1];
            AB[0][offX(kk1, m)] = f2bf(s_emb[ebase1 + idx * estr1]);
        }
        if (bx2) {
            int idx2 = input_time[((b0g + m) * ENC) * 4 + 3];
            AB[0][offX(kk2, m)] = f2bf(s_emb[ebase2 + idx2 * 7]);
        }
    }
    __syncthreads();

    // ============ encoder pipeline: iter i = layer0(i) + layer1(i-1) ========
    for (int i = 0; i <= ENC; ++i) {
        const ushort* Ar = AB[i & 1];
        ushort* Aw = AB[(i + 1) & 1];
        const bool active = isL0 ? (i < ENC) : (i >= 1);

        // prefetch globals for next x (L0 waves)
        float pre_f = 0.f; int pre_i1 = 0, pre_i2 = 0;
        const bool encX  = (i + 1 < ENC) && isL0;
        const bool decX0 = (i == ENC) && isL0;
        if (encX) {
            if (kk1 == 0) pre_f  = label_p[(b0g + m) * ENC + (i + 1)];
            else          pre_i1 = input_time[((b0g + m) * ENC + (i + 1)) * 4 + sel1];
            if (bx2)      pre_i2 = input_time[((b0g + m) * ENC + (i + 1)) * 4 + 3];
        } else if (decX0) {
            if (kk1 == 0) pre_f  = label_p[(b0g + m) * ENC + (ENC - 1)];
            else          pre_i1 = decoder_time[((b0g + m) * DEC) * 4 + sel1];
            if (bx2)      pre_i2 = decoder_time[((b0g + m) * DEC) * 4 + 3];
        }

        if (active) {
            // opaque zero: redefined every iteration so the staged-weight
            // LDS loads below can't be hoisted out of the loop (reg diet)
            unsigned zz = 0;
            asm volatile("" : "+v"(zz));
            f32x4 acc[4];
            bf16x8 wf[4];
            if (isL0) {
                bf16x8 ah[3];
#pragma unroll
                for (int c = 0; c < 3; c++)
                    ah[c] = *(const bf16x8*)(Ar + c * 512 + l * 8);
#pragma unroll
                for (int g = 0; g < 4; g++)
                    wf[g] = *(const bf16x8*)(sW + zz + g * 2048 + fbase);
#pragma unroll
                for (int g = 0; g < 4; g++)
                    acc[g] = __builtin_amdgcn_mfma_f32_16x16x32_bf16(
                        wA[0][g], ah[0], biasv[g], 0, 0, 0);
#pragma unroll
                for (int g = 0; g < 4; g++)
                    acc[g] = __builtin_amdgcn_mfma_f32_16x16x32_bf16(
                        wA[1][g], ah[1], acc[g], 0, 0, 0);
#pragma unroll
                for (int g = 0; g < 4; g++)
                    acc[g] = __builtin_amdgcn_mfma_f32_16x16x32_bf16(
                        wf[g], ah[2], acc[g], 0, 0, 0);
            } else {
                bf16x8 ah[4];
#pragma unroll
                for (int c = 0; c < 4; c++)
                    ah[c] = *(const bf16x8*)(Ar + (1 + c) * 512 + l * 8);
#pragma unroll
                for (int g = 0; g < 4; g++)
                    wf[g] = *(const bf16x8*)(sW + zz + 8192 + g * 2048 + fbase);
#pragma unroll
                for (int g = 0; g < 4; g++)
                    acc[g] = __builtin_amdgcn_mfma_f32_16x16x32_bf16(
                        wA[0][g], ah[0], biasv[g], 0, 0, 0);
#pragma unroll
                for (int g = 0; g < 4; g++)
                    acc[g] = __builtin_amdgcn_mfma_f32_16x16x32_bf16(
                        wA[1][g], ah[1], acc[g], 0, 0, 0);
#pragma unroll
                for (int g = 0; g < 4; g++)
                    acc[g] = __builtin_amdgcn_mfma_f32_16x16x32_bf16(
                        wf[g], ah[2], acc[g], 0, 0, 0);
#pragma unroll
                for (int g = 0; g < 4; g++)   // reuse wf regs for chunk 3
                    wf[g] = *(const bf16x8*)(sW + zz + 16384 + g * 2048 + fbase);
#pragma unroll
                for (int g = 0; g < 4; g++)
                    acc[g] = __builtin_amdgcn_mfma_f32_16x16x32_bf16(
                        wf[g], ah[3], acc[g], 0, 0, 0);
            }
            float hv[4];
#pragma unroll
            for (int r = 0; r < 4; r++)
                hv[r] = lstm_cell(acc[0][r], acc[1][r], acc[2][r], acc[3][r], cst[r]);
            store_h4(Aw, hoff, hv);    // single store: h0->c1c2 or h1->c3c4
        }
        if (encX || decX0) {
            if (kk1 == 0) store_prev(Aw, m, pre_f);
            else          Aw[offX(kk1, m)] = f2bf(s_emb[ebase1 + pre_i1 * estr1]);
            if (bx2)      Aw[offX(kk2, m)] = f2bf(s_emb[ebase2 + pre_i2 * 7]);
        }
        __syncthreads();
    }

    // ============ decoder: waves 4-7 (per half) compute; L0 waves build x ===
    {   // restage WD chunk 2 over the (now dead) W0 c2 region
        const uint* gd = (const uint*)(wsu + WDF + 2 * 8192);
        uint* d = (uint*)sW;
        for (int i = tid; i < 4096; i += 1024) d[i] = gd[i];
    }
    if (!isL0) {
#pragma unroll
        for (int c = 0; c < 2; c++)
#pragma unroll
            for (int g = 0; g < 4; g++)
                wA[c][g] = *(const bf16x8*)(wsu + WDF +
                    (c * 16 + g * 4 + wl) * 512 + l * 8);
#pragma unroll
        for (int c = 0; c < 2; c++)
#pragma unroll
            for (int g = 0; g < 4; g++) pinv(wA[c][g]);
#pragma unroll
        for (int g = 0; g < 4; g++) {
            biasv[g] = *(const f32x4*)(wsf + F_BD + g * 64 + u0);
            pinf(biasv[g]);
        }
    }
    __syncthreads();   // restaged sW visible to all before decoder reads

    for (int t = 0; t < DEC; ++t) {
        const ushort* Ar = AB[(t + 1) & 1];
        ushort* Aw = AB[t & 1];

        int pre_i1 = 0, pre_i2 = 0;
        const bool dX = (t + 1 < DEC) && isL0;
        if (dX) {
            if (kk1 >= 1) pre_i1 = decoder_time[((b0g + m) * DEC + (t + 1)) * 4 + sel1];
            if (bx2)      pre_i2 = decoder_time[((b0g + m) * DEC + (t + 1)) * 4 + 3];
        }

        if (!isL0) {
            unsigned zz = 0;
            asm volatile("" : "+v"(zz));
            bf16x8 ah[3];
            ah[0] = *(const bf16x8*)(Ar + 0 * 512 + l * 8);   // xin (c0)
            ah[1] = *(const bf16x8*)(Ar + 3 * 512 + l * 8);   // h1 lo (c3)
            ah[2] = *(const bf16x8*)(Ar + 4 * 512 + l * 8);   // h1 hi (c4)
            bf16x8 wf[4];
#pragma unroll
            for (int g = 0; g < 4; g++)
                wf[g] = *(const bf16x8*)(sW + zz + g * 2048 + fbase);
            f32x4 acc[4];
#pragma unroll
            for (int g = 0; g < 4; g++)
                acc[g] = __builtin_amdgcn_mfma_f32_16x16x32_bf16(
                    wA[0][g], ah[0], biasv[g], 0, 0, 0);
#pragma unroll
            for (int g = 0; g < 4; g++)
                acc[g] = __builtin_amdgcn_mfma_f32_16x16x32_bf16(
                    wA[1][g], ah[1], acc[g], 0, 0, 0);
#pragma unroll
            for (int g = 0; g < 4; g++)
                acc[g] = __builtin_amdgcn_mfma_f32_16x16x32_bf16(
                    wf[g], ah[2], acc[g], 0, 0, 0);
            float hv[4];
#pragma unroll
            for (int r = 0; r < 4; r++)
                hv[r] = lstm_cell(acc[0][r], acc[1][r], acc[2][r], acc[3][r], cst[r]);
            store_h4(Aw, hoff, hv);                 // h1 recurrent -> c3c4
            *(f32x4*)&myh1[m * 68 + u0] = *(f32x4*)hv;
        }
        if (dX && kk1 >= 1) Aw[offX(kk1, m)] = f2bf(s_emb[ebase1 + pre_i1 * estr1]);
        if (dX && bx2)      Aw[offX(kk2, m)] = f2bf(s_emb[ebase2 + pre_i2 * 7]);
        __syncthreads();

        if (stid < 16) {   // serial projection, verified summation order
            float a = s_bout;
#pragma unroll 16
            for (int u = 0; u < 64; u++) a = fmaf(s_wout[u], myh1[stid * 68 + u], a);
            out[(b0g + stid) * DEC + t] = a;
            if (t + 1 < DEC) store_prev(Aw, stid, a);  // fp32-accurate prev (hi+lo)
        }
        __syncthreads();
    }
}

extern "C" void kernel_launch(void* const* d_in, const int* in_sizes, int n_in,
                              void* d_out, int out_size, void* d_ws, size_t ws_size,
                              hipStream_t stream)
{
    typedef const float* fp;
    const int* input_time   = (const int*)d_in[1];
    fp         label_p      = (fp)d_in[2];
    const int* decoder_time = (const int*)d_in[3];

    prep_kernel<<<128, 256, 0, stream>>>(
        (fp)d_in[4],  (fp)d_in[5],  (fp)d_in[6],  (fp)d_in[7],
        (fp)d_in[8],  (fp)d_in[9],  (fp)d_in[10], (fp)d_in[11],
        (fp)d_in[12], (fp)d_in[13], (fp)d_in[14], (fp)d_in[15],
        (fp)d_in[16], (fp)d_in[17],
        (fp)d_in[18], (fp)d_in[19], (fp)d_in[20], (fp)d_in[21],
        d_ws);

    lstm_mfma<<<NBLK, 1024, 0, stream>>>(
        input_time, label_p, decoder_time, d_ws, (float*)d_out);
}

// Round 6
// 335.996 us; speedup vs baseline: 1.6133x; 1.2158x over previous
//
#include <hip/hip_runtime.h>

#define DEVFN __device__ __forceinline__

typedef float  f32x4  __attribute__((ext_vector_type(4)));
typedef short  bf16x8 __attribute__((ext_vector_type(8)));

// Problem constants
constexpr int ENC = 168;
constexpr int DEC = 24;
constexpr int BT  = 16;            // batch tile (MFMA N)
constexpr int NBLK = 4096 / BT;    // 256 blocks -> 1 per CU

constexpr float LOG2E  = 1.4426950408889634f;
constexpr float LOG2E2 = 2.8853900817779268f;

// Workspace layout: VERIFIED round-0 gate-major tile layout, UNCHANGED.
// Tile tt = g*4 + j holds gate g, units j*16..j*16+15 (n = tt*16 + row).
// K-maps: L0: k<20 x (c0), k==20 dup of col0 (lo-plane), k in[32,96) h0 (c1,c2)
//         L1: k<64 h0 (c1,c2), k in[64,128) h1 (c3,c4)
//         DEC: k<20 xin (c0), k==20 dup col0, k in[32,96) h1 (c3,c4)
constexpr int W0F = 0;             // 3*16*512 = 24576 ushorts
constexpr int W1F = 24576;         // 4*16*512 = 32768
constexpr int WDF = 57344;         // 3*16*512 = 24576
constexpr int F_B0   = 40960;
constexpr int F_B1   = 41216;
constexpr int F_BD   = 41472;
constexpr int F_WOUT = 41728;
constexpr int F_BOUT = 41792;
constexpr int F_EMB  = 41793;      // [574] hour120 wd24 mo52 woy378
constexpr int NEMB = 574;

DEVFN ushort f2bf(float v) {       // fp32 -> bf16 bits, RNE
    unsigned b = __float_as_uint(v);
    return (ushort)((b + 0x7FFFu + ((b >> 16) & 1u)) >> 16);
}
DEVFN float bf2f(ushort u) { return __uint_as_float(((unsigned)u) << 16); }
DEVFN float exp2n(float x) {       // 2^(-x), neg as free input modifier
    float r;
    asm("v_exp_f32 %0, -%1" : "=v"(r) : "v"(x));
    return r;
}
DEVFN void pinv(bf16x8& v) { asm volatile("" : "+v"(v)); }
DEVFN void pinf(f32x4& v)  { asm volatile("" : "+v"(v)); }

// LSTM cell on pre-scaled gates (i,f,o x log2e; g x 2log2e), fused-rcp pairs.
DEVFN float lstm_cell(float gi, float gf, float gg, float go, float& c) {
    float a  = exp2n(fmaxf(gi, -21.f));            // e^-i
    float b  = exp2n(fmaxf(gg, -43.f));            // e^-2g
    float f  = exp2n(gf);                          // e^-f
    float sf = __builtin_amdgcn_rcpf(1.f + f);
    float it = (1.f - b) * __builtin_amdgcn_rcpf(fmaf(a, b, a + b + 1.f));
    c = fmaf(sf, c, it);
    float d  = exp2n(fmaxf(c, -15.f) * LOG2E2);    // e^-2c
    float o  = exp2n(fmaxf(go, -21.f));            // e^-o
    return (1.f - d) * __builtin_amdgcn_rcpf(fmaf(o, d, o + d + 1.f));
}

// ---------------- prep: weights -> bf16 MFMA fragments (pre-scaled) --------
// EXACT layout of the verified round-0 kernel (gate-major tiles).
__global__ void prep_kernel(
    const float* __restrict__ w0ih, const float* __restrict__ w0hh,
    const float* __restrict__ b0ih, const float* __restrict__ b0hh,
    const float* __restrict__ w1ih, const float* __restrict__ w1hh,
    const float* __restrict__ b1ih, const float* __restrict__ b1hh,
    const float* __restrict__ wdih, const float* __restrict__ wdhh,
    const float* __restrict__ bdih, const float* __restrict__ bdhh,
    const float* __restrict__ wout, const float* __restrict__ boutp,
    const float* __restrict__ eh,   const float* __restrict__ ewd,
    const float* __restrict__ emo,  const float* __restrict__ ewoy,
    void* __restrict__ ws)
{
    ushort* wsu = (ushort*)ws;
    float*  wsf = (float*)ws;
    const int total = 81920 + 1407;
    for (int idx = blockIdx.x * blockDim.x + threadIdx.x; idx < total;
         idx += gridDim.x * blockDim.x) {
        if (idx < 81920) {
            int layer, q;
            if (idx < W1F)      { layer = 0; q = idx; }
            else if (idx < WDF) { layer = 1; q = idx - W1F; }
            else                { layer = 2; q = idx - WDF; }
            int c  = q >> 13;
            int tt = (q >> 9) & 15;
            int l  = (q >> 3) & 63;
            int j  = q & 7;
            int k  = c * 32 + (l >> 4) * 8 + j;
            int n  = tt * 16 + (l & 15);
            float v = 0.f;
            if (layer == 0) {
                if (k < 20) v = w0ih[n * 20 + k];
                else if (k == 20) v = w0ih[n * 20];            // lo-plane dup of col0
                else if (k >= 32 && k < 96) v = w0hh[n * 64 + (k - 32)];
            } else if (layer == 1) {
                if (k < 64) v = w1ih[n * 64 + k];
                else        v = w1hh[n * 64 + (k - 64)];
            } else {
                if (k < 20) v = wdih[n * 20 + k];
                else if (k == 20) v = wdih[n * 20];            // lo-plane dup of col0
                else if (k >= 32 && k < 96) v = wdhh[n * 64 + (k - 32)];
            }
            v *= ((n >> 6) == 2) ? LOG2E2 : LOG2E;   // pre-scale for exp2
            wsu[idx] = f2bf(v);
        } else {
            int f = idx - 81920;
            float v;
            if (f < 768) {
                float sc = (((f & 255) >> 6) == 2) ? LOG2E2 : LOG2E;
                if (f < 256)      v = (b0ih[f] + b0hh[f]) * sc;
                else if (f < 512) v = (b1ih[f - 256] + b1hh[f - 256]) * sc;
                else              v = (bdih[f - 512] + bdhh[f - 512]) * sc;
            }
            else if (f < 832) v = wout[f - 768];
            else if (f == 832) v = boutp[0];
            else {
                int e = f - 833;
                if (e < 120)      v = eh[e];
                else if (e < 144) v = ewd[e - 120];
                else if (e < 196) v = emo[e - 144];
                else              v = ewoy[e - 196];
            }
            wsf[40960 + f] = v;
        }
    }
}

DEVFN int offX(int k, int m) {     // chunk0 fragment offset, k in [0,32)
    return (m + 16 * (k >> 3)) * 8 + (k & 7);
}
// hi/lo pair for the k=0 feature (label/prev): hi at k=0, lo at k=20
DEVFN void store_prev(ushort* A, int m, float v) {
    ushort hi = f2bf(v);
    A[offX(0, m)]  = hi;
    A[offX(20, m)] = f2bf(v - bf2f(hi));
}

// ---------------- main persistent MFMA kernel: 1024 thr, 16 waves ----------
// Grid 256 (1 block/CU), BT=16 batches/block. The 32 MFMA tiles of round 0
// (16 L0 + 16 L1, gate-major prep layout UNCHANGED) are split one-per-wave:
// wave w computes L0 tile w (3 MFMAs) and L1 tile w (4 MFMAs), writes fp32
// gates to LDS planes G; after a barrier each thread runs exactly 2 LSTM
// cells (its (u,m) for L0 and L1). Same MFMA chains, same order, same
// fragments, same cell math -> BIT-IDENTICAL to round 0; per-wave work
// halves and waves/SIMD doubles (2->4) for latency hiding.
// LDS padded >81920 B: only 1 WG/CU fits, so the compiler's LDS-occupancy
// heuristic targets 4 waves/EU = 128-VGPR budget (round-2/5 spills were the
// allocator chasing an 8-wave target because 2 WGs fit in LDS).
__global__ __launch_bounds__(1024)
void lstm_mfma(
    const int* __restrict__ input_time, const float* __restrict__ label_p,
    const int* __restrict__ decoder_time, const void* __restrict__ ws,
    float* __restrict__ out)
{
    const ushort* wsu = (const ushort*)ws;
    const float*  wsf = (const float*)ws;

    // double-buffered activations: c0=x/xin, c1c2=h0, c3c4=h1 (bf16 frags)
    __shared__ __align__(16) ushort Abuf[2][5 * 512];
    // fp32 gate planes: [layer][gate][m][u] with u-stride 68 (bank spread)
    __shared__ __align__(16) float G[2][4][16][68];
    __shared__ float s_emb[NEMB];
    __shared__ float s_wout[64];
    __shared__ __align__(16) float sh1[16 * 68];   // [m][u] padded
    __shared__ float s_bout;
    __shared__ ushort s_pad[15360];    // 30720 B pad -> total LDS > 81920 B

    const int tid = threadIdx.x;
    const int w   = tid >> 6;          // wave 0..15 = tile tt
    const int l   = tid & 63;
    const int q   = l >> 4;
    const int m16 = l & 15;
    const int g   = w >> 2;            // tile's gate
    const int j   = w & 3;             // tile's unit block
    const int u0t = j * 16 + q * 4;    // lane's first unit within gate block
    const int cu  = (w << 2) | q;      // cell unit 0..63 (1 cell/thread/layer)
    const int cm  = m16;               // cell batch
    const int b0g = blockIdx.x * BT;

    // keep the LDS pad alive (opaque never-true condition)
    if (label_p == nullptr) ((volatile ushort*)s_pad)[tid & 1023] = 0;

    // h scalar store offsets (same element positions as round-0's b64 store)
    const int hoffL0 = (1 + (cu >> 5)) * 512 +
                       (cm + 16 * ((cu & 31) >> 3)) * 8 + (cu & 7);
    const int hoffL1 = hoffL0 + 1024;          // c3c4 instead of c1c2

    // ---- init ----
    for (int i2 = tid; i2 < 2 * 5 * 512; i2 += 1024) ((ushort*)Abuf)[i2] = 0;
    for (int i2 = tid; i2 < NEMB; i2 += 1024) s_emb[i2] = wsf[F_EMB + i2];
    if (tid < 64) s_wout[tid] = wsf[F_WOUT + tid];
    if (tid == 0) s_bout = wsf[F_BOUT];

    // ---- weight fragments: L0 tile w (3 chunks) + L1 tile w (4 chunks) ----
    bf16x8 wA0[3], wA1[4];
#pragma unroll
    for (int c = 0; c < 3; c++)
        wA0[c] = *(const bf16x8*)(wsu + W0F + (c * 16 + w) * 512 + l * 8);
#pragma unroll
    for (int c = 0; c < 4; c++)
        wA1[c] = *(const bf16x8*)(wsu + W1F + (c * 16 + w) * 512 + l * 8);
#pragma unroll
    for (int c = 0; c < 3; c++) pinv(wA0[c]);
#pragma unroll
    for (int c = 0; c < 4; c++) pinv(wA1[c]);

    f32x4 bias0 = *(const f32x4*)(wsf + F_B0 + g * 64 + u0t);
    f32x4 bias1 = *(const f32x4*)(wsf + F_B1 + g * 64 + u0t);
    pinf(bias0); pinf(bias1);

    float cstL0 = 0.f, cstL1 = 0.f;    // this thread's 2 cell states

    // x-build roles (identical to round 0): primary kk1 = tid>>4 for tid<256;
    // secondary kk2 = kk1+16 (16..19) for tid<64. batch = tid&15 = m16.
    const int kk1 = tid >> 4;
    const int kk2 = kk1 + 16;
    int sel1 = 0, estr1 = 0, ebase1 = 0;
    if (kk1 >= 1 && kk1 < 16) {
        int f = kk1 - 1;
        if (f < 5)       { sel1 = 0; estr1 = 5; ebase1 = 0   + f; }
        else if (f < 8)  { sel1 = 1; estr1 = 3; ebase1 = 120 + (f - 5); }
        else if (f < 12) { sel1 = 2; estr1 = 4; ebase1 = 144 + (f - 8); }
        else             { sel1 = 3; estr1 = 7; ebase1 = 196 + (f - 12); }
    }
    const int ebase2 = 196 + (kk2 - 13);   // woy table, stride 7

    __syncthreads();
    if (tid < 256) {    // x(0) into Abuf[0]
        if (kk1 == 0) {
            store_prev(Abuf[0], m16, label_p[(b0g + m16) * ENC]);
        } else {
            int idx = input_time[((b0g + m16) * ENC) * 4 + sel1];
            Abuf[0][offX(kk1, m16)] = f2bf(s_emb[ebase1 + idx * estr1]);
        }
    }
    if (tid < 64) {
        int idx2 = input_time[((b0g + m16) * ENC) * 4 + 3];
        Abuf[0][offX(kk2, m16)] = f2bf(s_emb[ebase2 + idx2 * 7]);
    }
    __syncthreads();

    // ============ encoder pipeline: iter i = layer0(i) + layer1(i-1) ========
    for (int i = 0; i <= ENC; ++i) {
        const ushort* Ar = Abuf[i & 1];
        ushort* Aw = Abuf[(i + 1) & 1];
        const bool actL0 = (i < ENC);
        const bool actL1 = (i >= 1);

        // prefetch globals for next x (consumed in phase 2 -> long window)
        float pre_f = 0.f; int pre_i1 = 0, pre_i2 = 0;
        const bool encX  = (i + 1 < ENC) && (tid < 256);
        const bool decX0 = (i == ENC) && (tid < 256);
        if (encX) {
            if (kk1 == 0) pre_f  = label_p[(b0g + m16) * ENC + (i + 1)];
            else          pre_i1 = input_time[((b0g + m16) * ENC + (i + 1)) * 4 + sel1];
            if (tid < 64) pre_i2 = input_time[((b0g + m16) * ENC + (i + 1)) * 4 + 3];
        } else if (decX0) {
            if (kk1 == 0) pre_f  = label_p[(b0g + m16) * ENC + (ENC - 1)];
            else          pre_i1 = decoder_time[((b0g + m16) * DEC) * 4 + sel1];
            if (tid < 64) pre_i2 = decoder_time[((b0g + m16) * DEC) * 4 + 3];
        }

        // ---- phase 1: MFMA gate tiles -> fp32 LDS planes ----
        {
            bf16x8 ah[5];
#pragma unroll
            for (int c = 0; c < 5; c++)
                ah[c] = *(const bf16x8*)(Ar + c * 512 + l * 8);
            if (actL0) {               // chain: c0(bias C-in), c1, c2
                f32x4 a0 = __builtin_amdgcn_mfma_f32_16x16x32_bf16(
                    wA0[0], ah[0], bias0, 0, 0, 0);
                a0 = __builtin_amdgcn_mfma_f32_16x16x32_bf16(
                    wA0[1], ah[1], a0, 0, 0, 0);
                a0 = __builtin_amdgcn_mfma_f32_16x16x32_bf16(
                    wA0[2], ah[2], a0, 0, 0, 0);
                *(f32x4*)&G[0][g][m16][u0t] = a0;
            }
            if (actL1) {               // chain: c1(bias C-in), c2, c3, c4
                f32x4 a1 = __builtin_amdgcn_mfma_f32_16x16x32_bf16(
                    wA1[0], ah[1], bias1, 0, 0, 0);
                a1 = __builtin_amdgcn_mfma_f32_16x16x32_bf16(
                    wA1[1], ah[2], a1, 0, 0, 0);
                a1 = __builtin_amdgcn_mfma_f32_16x16x32_bf16(
                    wA1[2], ah[3], a1, 0, 0, 0);
                a1 = __builtin_amdgcn_mfma_f32_16x16x32_bf16(
                    wA1[3], ah[4], a1, 0, 0, 0);
                *(f32x4*)&G[1][g][m16][u0t] = a1;
            }
        }
        __syncthreads();   // gates ready

        // ---- phase 2: cells (1 per layer per thread) + x-build writes ----
        if (actL0) {
            float h = lstm_cell(G[0][0][cm][cu], G[0][1][cm][cu],
                                G[0][2][cm][cu], G[0][3][cm][cu], cstL0);
            Aw[hoffL0] = f2bf(h);
        }
        if (actL1) {
            float h = lstm_cell(G[1][0][cm][cu], G[1][1][cm][cu],
                                G[1][2][cm][cu], G[1][3][cm][cu], cstL1);
            Aw[hoffL1] = f2bf(h);
        }
        if (encX || decX0) {
            if (kk1 == 0) store_prev(Aw, m16, pre_f);
            else          Aw[offX(kk1, m16)] = f2bf(s_emb[ebase1 + pre_i1 * estr1]);
            if (tid < 64) Aw[offX(kk2, m16)] = f2bf(s_emb[ebase2 + pre_i2 * 7]);
        }
        __syncthreads();   // Aw complete
    }

    // ============ decoder: all 16 waves on DEC tile w ======================
#pragma unroll
    for (int c = 0; c < 3; c++)
        wA0[c] = *(const bf16x8*)(wsu + WDF + (c * 16 + w) * 512 + l * 8);
#pragma unroll
    for (int c = 0; c < 3; c++) pinv(wA0[c]);
    bias0 = *(const f32x4*)(wsf + F_BD + g * 64 + u0t);
    pinf(bias0);

    for (int t = 0; t < DEC; ++t) {
        const ushort* Ar = Abuf[(t + 1) & 1];
        ushort* Aw = Abuf[t & 1];

        int pre_i1 = 0, pre_i2 = 0;
        const bool dX = (t + 1 < DEC) && (tid < 256);
        if (dX) {
            if (kk1 >= 1) pre_i1 = decoder_time[((b0g + m16) * DEC + (t + 1)) * 4 + sel1];
            if (tid < 64) pre_i2 = decoder_time[((b0g + m16) * DEC + (t + 1)) * 4 + 3];
        }

        // ---- phase 1: DEC gate MFMA ----
        {
            bf16x8 a0f = *(const bf16x8*)(Ar + 0 * 512 + l * 8);  // xin (c0)
            bf16x8 a1f = *(const bf16x8*)(Ar + 3 * 512 + l * 8);  // h1 lo (c3)
            bf16x8 a2f = *(const bf16x8*)(Ar + 4 * 512 + l * 8);  // h1 hi (c4)
            f32x4 a = __builtin_amdgcn_mfma_f32_16x16x32_bf16(
                wA0[0], a0f, bias0, 0, 0, 0);
            a = __builtin_amdgcn_mfma_f32_16x16x32_bf16(wA0[1], a1f, a, 0, 0, 0);
            a = __builtin_amdgcn_mfma_f32_16x16x32_bf16(wA0[2], a2f, a, 0, 0, 0);
            *(f32x4*)&G[1][g][m16][u0t] = a;
        }
        __syncthreads();

        // ---- phase 2: cells + sh1 + x-build writes ----
        {
            float h = lstm_cell(G[1][0][cm][cu], G[1][1][cm][cu],
                                G[1][2][cm][cu], G[1][3][cm][cu], cstL1);
            Aw[hoffL1] = f2bf(h);          // h1 recurrent -> c3c4
            sh1[cm * 68 + cu] = h;
        }
        if (dX && kk1 >= 1) Aw[offX(kk1, m16)] = f2bf(s_emb[ebase1 + pre_i1 * estr1]);
        if (dX && tid < 64) Aw[offX(kk2, m16)] = f2bf(s_emb[ebase2 + pre_i2 * 7]);
        __syncthreads();

        // ---- phase 3: projection (verified round-0 summation order) ----
        if (tid < 16) {
            float a = s_bout;
#pragma unroll 16
            for (int u = 0; u < 64; u++) a = fmaf(s_wout[u], sh1[tid * 68 + u], a);
            out[(b0g + tid) * DEC + t] = a;
            if (t + 1 < DEC) store_prev(Aw, tid, a);   // fp32-accurate prev
        }
        __syncthreads();
    }
}

extern "C" void kernel_launch(void* const* d_in, const int* in_sizes, int n_in,
                              void* d_out, int out_size, void* d_ws, size_t ws_size,
                              hipStream_t stream)
{
    typedef const float* fp;
    const int* input_time   = (const int*)d_in[1];
    fp         label_p      = (fp)d_in[2];
    const int* decoder_time = (const int*)d_in[3];

    prep_kernel<<<128, 256, 0, stream>>>(
        (fp)d_in[4],  (fp)d_in[5],  (fp)d_in[6],  (fp)d_in[7],
        (fp)d_in[8],  (fp)d_in[9],  (fp)d_in[10], (fp)d_in[11],
        (fp)d_in[12], (fp)d_in[13], (fp)d_in[14], (fp)d_in[15],
        (fp)d_in[16], (fp)d_in[17],
        (fp)d_in[18], (fp)d_in[19], (fp)d_in[20], (fp)d_in[21],
        d_ws);

    lstm_mfma<<<NBLK, 1024, 0, stream>>>(
        input_time, label_p, decoder_time, d_ws, (float*)d_out);
}

// Round 7
// 299.051 us; speedup vs baseline: 1.8126x; 1.1235x over previous
//
#include <hip/hip_runtime.h>

#define DEVFN __device__ __forceinline__

typedef float  f32x4  __attribute__((ext_vector_type(4)));
typedef short  bf16x8 __attribute__((ext_vector_type(8)));

// Problem constants
constexpr int ENC = 168;
constexpr int DEC = 24;
constexpr int BT  = 16;            // batch tile (MFMA N)
constexpr int NBLK = 4096 / BT;    // 256 blocks -> 1 per CU

constexpr float LOG2E  = 1.4426950408889634f;
constexpr float LOG2E2 = 2.8853900817779268f;

constexpr int NEMB = 574;          // hour120 wd24 mo52 woy378

DEVFN ushort f2bf(float v) {       // fp32 -> bf16 bits, RNE (scalar path)
    unsigned b = __float_as_uint(v);
    return (ushort)((b + 0x7FFFu + ((b >> 16) & 1u)) >> 16);
}
DEVFN float bf2f(ushort u) { return __uint_as_float(((unsigned)u) << 16); }
DEVFN unsigned cvt_pk_bf16(float a, float b) {  // hw packed RNE
    unsigned r;
    asm("v_cvt_pk_bf16_f32 %0, %1, %2" : "=v"(r) : "v"(a), "v"(b));
    return r;
}
DEVFN float exp2n(float x) {       // 2^(-x), neg as free input modifier
    float r;
    asm("v_exp_f32 %0, -%1" : "=v"(r) : "v"(x));
    return r;
}
// pin a value into registers: asm consumes+redefines it -> no remat of the load
DEVFN void pinv(bf16x8& v) { asm volatile("" : "+v"(v)); }
DEVFN void pinf(f32x4& v)  { asm volatile("" : "+v"(v)); }

// LSTM cell on pre-scaled gates (i,f,o x log2e; g x 2log2e), fused-rcp pairs.
DEVFN float lstm_cell(float gi, float gf, float gg, float go, float& c) {
    float a  = exp2n(fmaxf(gi, -21.f));            // e^-i
    float b  = exp2n(fmaxf(gg, -43.f));            // e^-2g
    float f  = exp2n(gf);                          // e^-f
    float sf = __builtin_amdgcn_rcpf(1.f + f);
    float it = (1.f - b) * __builtin_amdgcn_rcpf(fmaf(a, b, a + b + 1.f));
    c = fmaf(sf, c, it);
    float d  = exp2n(fmaxf(c, -15.f) * LOG2E2);    // e^-2c
    float o  = exp2n(fmaxf(go, -21.f));            // e^-o
    return (1.f - d) * __builtin_amdgcn_rcpf(fmaf(o, d, o + d + 1.f));
}

// ---- in-kernel fragment builders: EXACT prep_kernel values (f2bf(v*sc)) ----
// Fragment element (chunk c, tile tt=g*4+wl, lane l, j): row n = tt*16+(l&15),
// k = c*32 + (l>>4)*8 + j. Same K-maps as the verified round-0 prep:
//   20-input layers (L0/DEC): k<20 ih; k==20 dup of ih col0 (lo-plane);
//   32<=k<96 hh. 64-input layer (L1): k<64 ih; 64<=k<128 hh.
DEVFN bf16x8 frag20(const float* __restrict__ wih, const float* __restrict__ whh,
                    int n, int c, int kq, float sc) {
    bf16x8 r;
#pragma unroll
    for (int j = 0; j < 8; j++) {
        int k = c * 32 + kq + j;
        float v = 0.f;
        if (k < 20)                 v = wih[n * 20 + k];
        else if (k == 20)           v = wih[n * 20];
        else if (k >= 32 && k < 96) v = whh[n * 64 + (k - 32)];
        r[j] = (short)f2bf(v * sc);
    }
    return r;
}
DEVFN bf16x8 frag64(const float* __restrict__ wih, const float* __restrict__ whh,
                    int n, int c, int kq, float sc) {
    bf16x8 r;
#pragma unroll
    for (int j = 0; j < 8; j++) {
        int k = c * 32 + kq + j;
        float v = (k < 64) ? wih[n * 64 + k] : whh[n * 64 + (k - 64)];
        r[j] = (short)f2bf(v * sc);
    }
    return r;
}

DEVFN int offX(int k, int m) {     // chunk0 fragment offset, k in [0,32)
    return (m + 16 * (k >> 3)) * 8 + (k & 7);
}
// packed: 4 consecutive-k h values -> one b64 write
DEVFN void store_h4(ushort* A, int off, const float* h) {
    unsigned h01 = cvt_pk_bf16(h[0], h[1]);
    unsigned h23 = cvt_pk_bf16(h[2], h[3]);
    asm volatile("" : "+v"(h01), "+v"(h23));
    unsigned long long p = ((unsigned long long)h23 << 32) | h01;
    *(unsigned long long*)(A + off) = p;
}
// hi/lo pair for the k=0 feature (label/prev): hi at k=0, lo at k=20
DEVFN void store_prev(ushort* A, int m, float v) {
    ushort hi = f2bf(v);
    A[offX(0, m)]  = hi;
    A[offX(20, m)] = f2bf(v - bf2f(hi));
}

// ---------------- main persistent MFMA kernel: 512 thr ---------------------
// VERBATIM round-0 structure (206 us kernel, math-graph family absmax
// 2.441406e-04 confirmed by r2/r5/r6 rebuilds). Single launch: the prep
// kernel is fused as per-block self-prep (identical f2bf(v*sc) bits), which
// removes the ~75-83 us prep+second-launch overhead seen in every round.
// Waves 0-3: layer0 (encoder) + x-build. Waves 4-7: layer1 (enc) then decoder.
// Wave wl computes gate tiles {gamma*4+wl}: lane (q,m) owns all 4 gates of
// units u0..u0+3 (u0=wl*16+q*4) for batch m -> lane-local cell update.
__global__ __launch_bounds__(512)
__attribute__((amdgpu_waves_per_eu(2, 2)))
void lstm_mfma(
    const int* __restrict__ input_time, const float* __restrict__ label_p,
    const int* __restrict__ decoder_time,
    const float* __restrict__ w0ih, const float* __restrict__ w0hh,
    const float* __restrict__ b0ih, const float* __restrict__ b0hh,
    const float* __restrict__ w1ih, const float* __restrict__ w1hh,
    const float* __restrict__ b1ih, const float* __restrict__ b1hh,
    const float* __restrict__ wdih, const float* __restrict__ wdhh,
    const float* __restrict__ bdih, const float* __restrict__ bdhh,
    const float* __restrict__ wout, const float* __restrict__ boutp,
    const float* __restrict__ eh,   const float* __restrict__ ewd,
    const float* __restrict__ emo,  const float* __restrict__ ewoy,
    float* __restrict__ out)
{
    // double-buffered activations: c0=x/xin, c1c2=h0, c3c4=h1 (bf16 frags)
    __shared__ __align__(16) ushort Abuf[2][5 * 512];
    __shared__ float s_emb[NEMB];
    __shared__ float s_wout[64];
    __shared__ float sh1[16 * 68];     // [m][u] padded
    __shared__ float s_bout;

    const int tid = threadIdx.x;
    const int w   = tid >> 6;          // wave 0..7
    const int l   = tid & 63;
    const int q   = l >> 4;
    const int m   = l & 15;
    const int wl  = w & 3;
    const bool isL0 = (w < 4);
    const int b0g = blockIdx.x * BT;
    const int u0  = wl * 16 + q * 4;   // this lane's 4 units
    const int row = l & 15;            // fragment row within tile
    const int kq  = (l >> 4) * 8;      // fragment k-subblock base

    // h fragment store offset: L0 -> c1c2 (base), L1/dec -> c3c4 (+1024)
    const int hoff = (1 + (u0 >> 5)) * 512 +
                     (m + 16 * ((u0 & 31) >> 3)) * 8 + (u0 & 7) +
                     (isL0 ? 0 : 1024);

    // ---- init ----
    for (int i = tid; i < 2 * 5 * 512; i += 512) ((ushort*)Abuf)[i] = 0;
    for (int i = tid; i < NEMB; i += 512) {
        float v;
        if (i < 120)      v = eh[i];
        else if (i < 144) v = ewd[i - 120];
        else if (i < 196) v = emo[i - 144];
        else              v = ewoy[i - 196];
        s_emb[i] = v;
    }
    if (tid < 64) s_wout[tid] = wout[tid];
    if (tid == 0) s_bout = boutp[0];

    // ---- weight fragments (A-operand, bf16), self-prepped, reg-resident ----
    bf16x8 wA[4][4];                   // [chunk][gamma]; L0/dec use [0..2][*]
    if (isL0) {
#pragma unroll
        for (int c = 0; c < 3; c++)
#pragma unroll
            for (int g = 0; g < 4; g++)
                wA[c][g] = frag20(w0ih, w0hh, (g * 4 + wl) * 16 + row, c, kq,
                                  (g == 2) ? LOG2E2 : LOG2E);
        wA[3][0] = wA[3][1] = wA[3][2] = wA[3][3] = bf16x8{0,0,0,0,0,0,0,0};
    } else {
#pragma unroll
        for (int c = 0; c < 4; c++)
#pragma unroll
            for (int g = 0; g < 4; g++)
                wA[c][g] = frag64(w1ih, w1hh, (g * 4 + wl) * 16 + row, c, kq,
                                  (g == 2) ? LOG2E2 : LOG2E);
    }
#pragma unroll
    for (int c = 0; c < 4; c++)
#pragma unroll
        for (int g = 0; g < 4; g++) pinv(wA[c][g]);

    f32x4 biasv[4];
#pragma unroll
    for (int g = 0; g < 4; g++) {
        const float sc = (g == 2) ? LOG2E2 : LOG2E;
        const float* bi = isL0 ? b0ih : b1ih;
        const float* bh = isL0 ? b0hh : b1hh;
        f32x4 bv;
#pragma unroll
        for (int r = 0; r < 4; r++)
            bv[r] = (bi[g * 64 + u0 + r] + bh[g * 64 + u0 + r]) * sc;
        biasv[g] = bv;
        pinf(biasv[g]);
    }

    float cst[4] = {0.f, 0.f, 0.f, 0.f};

    // x-build roles (L0 waves only): primary kk1 = tid>>4 (0..15);
    // secondary kk2 = kk1+16 (16..19) for tid<64. batch = tid&15 = m.
    const int kk1 = tid >> 4;
    const int kk2 = kk1 + 16;
    const bool bx2 = (tid < 64);
    // hoisted emb addressing: lookup = s_emb[ebase + idx*estr]
    int sel1 = 0, estr1 = 0, ebase1 = 0;
    if (kk1 >= 1) {
        int f = kk1 - 1;
        if (f < 5)       { sel1 = 0; estr1 = 5; ebase1 = 0   + f; }
        else if (f < 8)  { sel1 = 1; estr1 = 3; ebase1 = 120 + (f - 5); }
        else if (f < 12) { sel1 = 2; estr1 = 4; ebase1 = 144 + (f - 8); }
        else             { sel1 = 3; estr1 = 7; ebase1 = 196 + (f - 12); }
    }
    const int ebase2 = 196 + (kk2 - 13);   // woy table, stride 7

    __syncthreads();
    if (isL0) {    // x(0) into Abuf[0]
        if (kk1 == 0) {
            store_prev(Abuf[0], m, label_p[(b0g + m) * ENC]);
        } else {
            int idx = input_time[((b0g + m) * ENC) * 4 + sel1];
            Abuf[0][offX(kk1, m)] = f2bf(s_emb[ebase1 + idx * estr1]);
        }
        if (bx2) {
            int idx2 = input_time[((b0g + m) * ENC) * 4 + 3];
            Abuf[0][offX(kk2, m)] = f2bf(s_emb[ebase2 + idx2 * 7]);
        }
    }
    __syncthreads();

    // ============ encoder pipeline: iter i = layer0(i) + layer1(i-1) ========
    for (int i = 0; i <= ENC; ++i) {
        const ushort* Ar = Abuf[i & 1];
        ushort* Aw = Abuf[(i + 1) & 1];
        const bool active = isL0 ? (i < ENC) : (i >= 1);

        // prefetch globals for next x (L0 waves)
        float pre_f = 0.f; int pre_i1 = 0, pre_i2 = 0;
        const bool encX  = (i + 1 < ENC) && isL0;
        const bool decX0 = (i == ENC) && isL0;
        if (encX) {
            if (kk1 == 0) pre_f  = label_p[(b0g + m) * ENC + (i + 1)];
            else          pre_i1 = input_time[((b0g + m) * ENC + (i + 1)) * 4 + sel1];
            if (bx2)      pre_i2 = input_time[((b0g + m) * ENC + (i + 1)) * 4 + 3];
        } else if (decX0) {
            if (kk1 == 0) pre_f  = label_p[(b0g + m) * ENC + (ENC - 1)];
            else          pre_i1 = decoder_time[((b0g + m) * DEC) * 4 + sel1];
            if (bx2)      pre_i2 = decoder_time[((b0g + m) * DEC) * 4 + 3];
        }

        if (active) {
            f32x4 acc[4];
            if (isL0) {
                bf16x8 ah[3];
#pragma unroll
                for (int c = 0; c < 3; c++)
                    ah[c] = *(const bf16x8*)(Ar + c * 512 + l * 8);
#pragma unroll
                for (int g = 0; g < 4; g++)
                    acc[g] = __builtin_amdgcn_mfma_f32_16x16x32_bf16(
                        wA[0][g], ah[0], biasv[g], 0, 0, 0);
#pragma unroll
                for (int c = 1; c < 3; c++)
#pragma unroll
                    for (int g = 0; g < 4; g++)
                        acc[g] = __builtin_amdgcn_mfma_f32_16x16x32_bf16(
                            wA[c][g], ah[c], acc[g], 0, 0, 0);
            } else {
                bf16x8 ah[4];
#pragma unroll
                for (int c = 0; c < 4; c++)
                    ah[c] = *(const bf16x8*)(Ar + (1 + c) * 512 + l * 8);
#pragma unroll
                for (int g = 0; g < 4; g++)
                    acc[g] = __builtin_amdgcn_mfma_f32_16x16x32_bf16(
                        wA[0][g], ah[0], biasv[g], 0, 0, 0);
#pragma unroll
                for (int c = 1; c < 4; c++)
#pragma unroll
                    for (int g = 0; g < 4; g++)
                        acc[g] = __builtin_amdgcn_mfma_f32_16x16x32_bf16(
                            wA[c][g], ah[c], acc[g], 0, 0, 0);
            }
            float hv[4];
#pragma unroll
            for (int r = 0; r < 4; r++)
                hv[r] = lstm_cell(acc[0][r], acc[1][r], acc[2][r], acc[3][r], cst[r]);
            store_h4(Aw, hoff, hv);    // single store: h0->c1c2 or h1->c3c4
        }
        if (encX || decX0) {
            if (kk1 == 0) store_prev(Aw, m, pre_f);
            else          Aw[offX(kk1, m)] = f2bf(s_emb[ebase1 + pre_i1 * estr1]);
            if (bx2)      Aw[offX(kk2, m)] = f2bf(s_emb[ebase2 + pre_i2 * 7]);
        }
        __syncthreads();
    }

    // ============ decoder: waves 4-7 compute (own c1); L0 waves build x =====
    if (!isL0) {
#pragma unroll
        for (int c = 0; c < 3; c++)
#pragma unroll
            for (int g = 0; g < 4; g++)
                wA[c][g] = frag20(wdih, wdhh, (g * 4 + wl) * 16 + row, c, kq,
                                  (g == 2) ? LOG2E2 : LOG2E);
#pragma unroll
        for (int c = 0; c < 3; c++)
#pragma unroll
            for (int g = 0; g < 4; g++) pinv(wA[c][g]);
#pragma unroll
        for (int g = 0; g < 4; g++) {
            const float sc = (g == 2) ? LOG2E2 : LOG2E;
            f32x4 bv;
#pragma unroll
            for (int r = 0; r < 4; r++)
                bv[r] = (bdih[g * 64 + u0 + r] + bdhh[g * 64 + u0 + r]) * sc;
            biasv[g] = bv;
            pinf(biasv[g]);
        }
    }

    for (int t = 0; t < DEC; ++t) {
        const ushort* Ar = Abuf[(t + 1) & 1];
        ushort* Aw = Abuf[t & 1];

        int pre_i1 = 0, pre_i2 = 0;
        const bool dX = (t + 1 < DEC) && isL0;
        if (dX) {
            if (kk1 >= 1) pre_i1 = decoder_time[((b0g + m) * DEC + (t + 1)) * 4 + sel1];
            if (bx2)      pre_i2 = decoder_time[((b0g + m) * DEC + (t + 1)) * 4 + 3];
        }

        if (!isL0) {
            bf16x8 ah[3];
            ah[0] = *(const bf16x8*)(Ar + 0 * 512 + l * 8);   // xin (c0)
            ah[1] = *(const bf16x8*)(Ar + 3 * 512 + l * 8);   // h1 lo (c3)
            ah[2] = *(const bf16x8*)(Ar + 4 * 512 + l * 8);   // h1 hi (c4)
            f32x4 acc[4];
#pragma unroll
            for (int g = 0; g < 4; g++)
                acc[g] = __builtin_amdgcn_mfma_f32_16x16x32_bf16(
                    wA[0][g], ah[0], biasv[g], 0, 0, 0);
#pragma unroll
            for (int c = 1; c < 3; c++)
#pragma unroll
                for (int g = 0; g < 4; g++)
                    acc[g] = __builtin_amdgcn_mfma_f32_16x16x32_bf16(
                        wA[c][g], ah[c], acc[g], 0, 0, 0);
            float hv[4];
#pragma unroll
            for (int r = 0; r < 4; r++)
                hv[r] = lstm_cell(acc[0][r], acc[1][r], acc[2][r], acc[3][r], cst[r]);
            store_h4(Aw, hoff, hv);                 // h1 recurrent -> c3c4
            *(f32x4*)&sh1[m * 68 + u0] = *(f32x4*)hv;
        }
        if (dX && kk1 >= 1) Aw[offX(kk1, m)] = f2bf(s_emb[ebase1 + pre_i1 * estr1]);
        if (dX && bx2)      Aw[offX(kk2, m)] = f2bf(s_emb[ebase2 + pre_i2 * 7]);
        __syncthreads();

        if (tid < 16) {   // serial projection, verified summation order
            float a = s_bout;
#pragma unroll 16
            for (int u = 0; u < 64; u++) a = fmaf(s_wout[u], sh1[tid * 68 + u], a);
            out[(b0g + tid) * DEC + t] = a;
            if (t + 1 < DEC) store_prev(Aw, tid, a);   // fp32-accurate prev (hi+lo)
        }
        __syncthreads();
    }
}

extern "C" void kernel_launch(void* const* d_in, const int* in_sizes, int n_in,
                              void* d_out, int out_size, void* d_ws, size_t ws_size,
                              hipStream_t stream)
{
    typedef const float* fp;
    lstm_mfma<<<NBLK, 512, 0, stream>>>(
        (const int*)d_in[1],  (fp)d_in[2],  (const int*)d_in[3],
        (fp)d_in[4],  (fp)d_in[5],  (fp)d_in[6],  (fp)d_in[7],
        (fp)d_in[8],  (fp)d_in[9],  (fp)d_in[10], (fp)d_in[11],
        (fp)d_in[12], (fp)d_in[13], (fp)d_in[14], (fp)d_in[15],
        (fp)d_in[16], (fp)d_in[17],
        (fp)d_in[18], (fp)d_in[19], (fp)d_in[20], (fp)d_in[21],
        (float*)d_out);
}